// Round 2
// baseline (1072.349 us; speedup 1.0000x reference)
//
#include <hip/hip_runtime.h>
#include <math.h>

#define BB 4
#define NN 4096
#define KK 16
#define CIN 32
#define COUT 64
#define BN_INV 0.9999950000375f

// ---------------- P0: derived W1 weights ----------------
__global__ void p0_weights(const float* __restrict__ W1,
                           float* __restrict__ Aw, float* __restrict__ Bw,
                           float* __restrict__ w1d) {
    int t = threadIdx.x;
    for (int i = t; i < 64 * 32; i += 256) {
        int o = i >> 5, c = i & 31;
        Aw[i] = W1[o * 128 + c] - W1[o * 128 + 64 + c];
        Bw[i] = W1[o * 128 + 32 + c] + W1[o * 128 + 64 + c];
    }
    if (t < 64) {
        float s = 0.f;
        for (int c = 96; c < 128; ++c) s += W1[t * 128 + c];
        w1d[t] = s;
    }
}

// ---------------- P1: transpose features to [B,N,32] ----------------
__global__ void p1_transpose(const float* __restrict__ f,
                             float* __restrict__ pT) {
    int g = blockIdx.x * 256 + threadIdx.x;  // b*N + n
    int b = g / NN, n = g % NN;
    float v[CIN];
#pragma unroll
    for (int c = 0; c < CIN; ++c) v[c] = f[(b * CIN + c) * NN + n];
#pragma unroll
    for (int c = 0; c < CIN; ++c) pT[(size_t)g * CIN + c] = v[c];
}

// ---------------- P2: per-point projections ctrA = A*p, nbrB = B*p ----------------
__global__ __launch_bounds__(256) void p2_proj(const float* __restrict__ pT,
                                               const float* __restrict__ Aw,
                                               const float* __restrict__ Bw,
                                               float* __restrict__ ctrA,
                                               float* __restrict__ nbrB) {
    __shared__ float sA[32 * 64], sB[32 * 64];
    for (int i = threadIdx.x; i < 2048; i += 256) {
        int o = i >> 5, c = i & 31;
        sA[c * 64 + o] = Aw[i];
        sB[c * 64 + o] = Bw[i];
    }
    __syncthreads();
    int g = blockIdx.x * 256 + threadIdx.x;  // (b*N+n)*64 + o
    int o = g & 63;
    int pn = g >> 6;
    const float* p = pT + (size_t)pn * 32;
    float a = 0.f, bb = 0.f;
#pragma unroll
    for (int c = 0; c < 32; ++c) {
        float pv = p[c];
        a = fmaf(sA[c * 64 + o], pv, a);
        bb = fmaf(sB[c * 64 + o], pv, bb);
    }
    ctrA[g] = a;
    nbrB[g] = bb;
}

// ---------------- KNN: top-16 by neg squared distance, fp64 ranking ----------------
#define QPB 32  // queries per block
#define SL 8    // candidate slices per query
#define TC 128  // candidates per LDS tile

// stable insert: descending values; on equal value smaller index first (lax.top_k)
#define TOPK_INSERT(VARR, IARR, DV, MI)                                     \
    if ((DV) > VARR[15] || ((DV) == VARR[15] && (MI) < IARR[15])) {         \
        double cv_ = (DV); int ci_ = (MI);                                  \
        _Pragma("unroll")                                                   \
        for (int j_ = 0; j_ < 16; ++j_) {                                   \
            if (cv_ > VARR[j_] || (cv_ == VARR[j_] && ci_ < IARR[j_])) {    \
                double tv_ = VARR[j_]; VARR[j_] = cv_; cv_ = tv_;           \
                int ti_ = IARR[j_]; IARR[j_] = ci_; ci_ = ti_;              \
            }                                                               \
        }                                                                   \
    }

__global__ __launch_bounds__(256) void knn_kernel(const float* __restrict__ pT,
                                                  int* __restrict__ fidx,
                                                  float* __restrict__ fdist) {
    // LDS union: phase A: tile fp32 [TC*32] (16KB) + tsq double[TC] (1KB)
    //            phase B: mval double[QPB*SL*16] (32KB) + midx int[4096] (16KB)
    __shared__ char smem[49152];
    float* tile = (float*)smem;
    double* tsq = (double*)(smem + 16384);
    double* mval = (double*)smem;
    int* midx = (int*)(smem + 32768);

    int tid = threadIdx.x;
    int q = tid & (QPB - 1);
    int s = tid >> 5;  // slice 0..7
    int b = blockIdx.x / (NN / QPB);
    int n = (blockIdx.x % (NN / QPB)) * QPB + q;
    const float* pbase = pT + (size_t)b * NN * 32;

    double qv[32];
#pragma unroll
    for (int c = 0; c < 32; ++c) qv[c] = (double)pbase[(size_t)n * 32 + c];
    double sqn = 0.0;
#pragma unroll
    for (int c = 0; c < 32; ++c) sqn = fma(qv[c], qv[c], sqn);

    double val[16];
    int idx[16];
#pragma unroll
    for (int i = 0; i < 16; ++i) { val[i] = -1e300; idx[i] = 0x7fffffff; }

    for (int m0 = 0; m0 < NN; m0 += TC) {
        __syncthreads();
        for (int i = tid; i < TC * 8; i += 256)
            ((float4*)tile)[i] = ((const float4*)(pbase + (size_t)m0 * 32))[i];
        __syncthreads();
        if (tid < TC) {
            double ss = 0.0;
            const float* tr = tile + tid * 32;
#pragma unroll
            for (int c = 0; c < 32; ++c) ss = fma((double)tr[c], (double)tr[c], ss);
            tsq[tid] = ss;
        }
        __syncthreads();
        for (int mm = s; mm < TC; mm += SL) {
            const float4* t4 = (const float4*)(tile + mm * 32);
            double dot = 0.0;
#pragma unroll
            for (int c4 = 0; c4 < 8; ++c4) {
                float4 tv = t4[c4];
                dot = fma((double)tv.x, qv[c4 * 4 + 0], dot);
                dot = fma((double)tv.y, qv[c4 * 4 + 1], dot);
                dot = fma((double)tv.z, qv[c4 * 4 + 2], dot);
                dot = fma((double)tv.w, qv[c4 * 4 + 3], dot);
            }
            double d = 2.0 * dot - sqn - tsq[mm];  // self -> exactly 0 (same chains)
            int m = m0 + mm;
            TOPK_INSERT(val, idx, d, m)
        }
    }
    __syncthreads();  // done reading tile; reuse LDS for merge
#pragma unroll
    for (int i = 0; i < 16; ++i) {
        mval[(q * SL + s) * 16 + i] = val[i];
        midx[(q * SL + s) * 16 + i] = idx[i];
    }
    __syncthreads();
    if (s == 0) {
        double fv[16];
        int fi[16];
#pragma unroll
        for (int i = 0; i < 16; ++i) { fv[i] = -1e300; fi[i] = 0x7fffffff; }
        for (int u = 0; u < SL * 16; ++u) {
            double cv = mval[q * SL * 16 + u];
            int ci = midx[q * SL * 16 + u];
            TOPK_INSERT(fv, fi, cv, ci)
        }
#pragma unroll
        for (int i = 0; i < 16; ++i) {
            fdist[((size_t)b * NN + n) * 16 + i] = (float)fv[i];
            fidx[((size_t)b * NN + n) * 16 + i] = fi[i];
        }
    }
}

// ---------------- Fused main pipeline: one thread per (b,n,k) ----------------
__global__ __launch_bounds__(256) void fuse_kernel(
    const float* __restrict__ coords, const float* __restrict__ feat,
    const int* __restrict__ knn_idx, const float* __restrict__ knn_dist,
    const float* __restrict__ W2, const float* __restrict__ W3,
    const float* __restrict__ W4, const float* __restrict__ W5,
    const float* __restrict__ g1, const float* __restrict__ b1,
    const float* __restrict__ g2, const float* __restrict__ b2,
    const float* __restrict__ g3, const float* __restrict__ b3,
    const float* __restrict__ g4, const float* __restrict__ b4,
    const float* __restrict__ g5, const float* __restrict__ b5,
    const float* __restrict__ ctrA, const float* __restrict__ nbrB,
    const float* __restrict__ w1d, const int* __restrict__ fidx,
    const float* __restrict__ fdist, float* __restrict__ out) {
    int g = blockIdx.x * 256 + threadIdx.x;
    int k = g & 15;
    int n = (g >> 4) & (NN - 1);
    int b = g >> 16;
    int pn = b * NN + n;

    int fnb = fidx[(size_t)pn * 16 + k];
    float fd = fdist[(size_t)pn * 16 + k];
    const float* cA = ctrA + (size_t)pn * 64;
    const float* nB = nbrB + ((size_t)b * NN + fnb) * 64;

    // features_knn (64) = leaky(BN(W1 . edge))
    float fk[64];
#pragma unroll
    for (int o = 0; o < 64; ++o) {
        float y = cA[o] + nB[o] + w1d[o] * fd;
        float v = fmaf(g1[o] * BN_INV, y, b1[o]);
        fk[o] = v > 0.f ? v : 0.2f * v;
    }

    // features_offset (3) = elu(BN(W2 . fk))
    float cq[3], cn_[3];
#pragma unroll
    for (int j = 0; j < 3; ++j) cq[j] = coords[(size_t)pn * 3 + j];
    int cnb = knn_idx[(size_t)pn * 16 + k];
#pragma unroll
    for (int j = 0; j < 3; ++j) cn_[j] = coords[((size_t)b * NN + cnb) * 3 + j];
    float kd = knn_dist[(size_t)pn * 16 + k];

    float cp[13];
#pragma unroll
    for (int j = 0; j < 3; ++j) {
        float a = 0.f;
#pragma unroll
        for (int o = 0; o < 64; ++o) a = fmaf(W2[j * 64 + o], fk[o], a);
        float t = fmaf(g2[j] * BN_INV, a, b2[j]);
        t = t > 0.f ? t : expm1f(t);  // elu
        cp[j] = cq[j];
        cp[3 + j] = cn_[j];
        cp[6 + j] = cq[j] - cn_[j];
        cp[10 + j] = t + cq[j];  // point_e
    }
    cp[9] = kd;

    // point_offset -> features_e ; out_point
    float fe[32];
#pragma unroll
    for (int c = 0; c < 32; ++c) {
        float a3 = 0.f, a4 = 0.f;
#pragma unroll
        for (int j = 0; j < 13; ++j) {
            a3 = fmaf(W3[c * 13 + j], cp[j], a3);
            a4 = fmaf(W4[c * 13 + j], cp[j], a4);
        }
        float po = fmaf(g3[c] * BN_INV, a3, b3[c]);
        po = po > 0.f ? po : expm1f(po);
        fe[c] = po + feat[(b * 32 + c) * NN + n];
        float op = fmaf(g4[c] * BN_INV, a4, b4[c]);
        op = op > 0.f ? op : expm1f(op);
        out[(((size_t)b * 64 + c) * NN + n) * 16 + k] = op;
    }

    // out_feature = elu(BN(W5 . [fk(64), fe(32)]))
#pragma unroll
    for (int c = 0; c < 32; ++c) {
        float a5 = 0.f;
#pragma unroll
        for (int o = 0; o < 64; ++o) a5 = fmaf(W5[c * 96 + o], fk[o], a5);
#pragma unroll
        for (int j = 0; j < 32; ++j) a5 = fmaf(W5[c * 96 + 64 + j], fe[j], a5);
        float v = fmaf(g5[c] * BN_INV, a5, b5[c]);
        v = v > 0.f ? v : expm1f(v);
        out[(((size_t)b * 64 + 32 + c) * NN + n) * 16 + k] = v;
    }
}

extern "C" void kernel_launch(void* const* d_in, const int* in_sizes, int n_in,
                              void* d_out, int out_size, void* d_ws, size_t ws_size,
                              hipStream_t stream) {
    const float* coords   = (const float*)d_in[0];
    const float* features = (const float*)d_in[1];
    const int*   knn_idx  = (const int*)d_in[2];
    const float* knn_dist = (const float*)d_in[3];
    const float* W1 = (const float*)d_in[4];
    const float* W2 = (const float*)d_in[5];
    const float* W3 = (const float*)d_in[6];
    const float* W4 = (const float*)d_in[7];
    const float* W5 = (const float*)d_in[8];
    const float* g1 = (const float*)d_in[9];
    const float* b1 = (const float*)d_in[10];
    const float* g2 = (const float*)d_in[11];
    const float* b2 = (const float*)d_in[12];
    const float* g3 = (const float*)d_in[13];
    const float* b3 = (const float*)d_in[14];
    const float* g4 = (const float*)d_in[15];
    const float* b4 = (const float*)d_in[16];
    const float* g5 = (const float*)d_in[17];
    const float* b5 = (const float*)d_in[18];
    float* out = (float*)d_out;

    // workspace layout (floats)
    float* pT    = (float*)d_ws;               // B*N*32  = 524288
    float* ctrA  = pT + BB * NN * 32;          // B*N*64  = 1048576
    float* nbrB  = ctrA + BB * NN * 64;        // B*N*64  = 1048576
    float* fdist = nbrB + BB * NN * 64;        // B*N*16  = 262144
    float* Aw    = fdist + BB * NN * 16;       // 2048
    float* Bw    = Aw + 2048;                  // 2048
    float* w1d   = Bw + 2048;                  // 64
    int*   fidx  = (int*)(w1d + 64);           // B*N*16  = 262144

    hipLaunchKernelGGL(p0_weights, dim3(1), dim3(256), 0, stream, W1, Aw, Bw, w1d);
    hipLaunchKernelGGL(p1_transpose, dim3(BB * NN / 256), dim3(256), 0, stream,
                       features, pT);
    hipLaunchKernelGGL(p2_proj, dim3(BB * NN * 64 / 256), dim3(256), 0, stream,
                       pT, Aw, Bw, ctrA, nbrB);
    hipLaunchKernelGGL(knn_kernel, dim3(BB * (NN / QPB)), dim3(256), 0, stream,
                       pT, fidx, fdist);
    hipLaunchKernelGGL(fuse_kernel, dim3(BB * NN * KK / 256), dim3(256), 0, stream,
                       coords, features, knn_idx, knn_dist, W2, W3, W4, W5,
                       g1, b1, g2, b2, g3, b3, g4, b4, g5, b5,
                       ctrA, nbrB, w1d, fidx, fdist, out);
}

// Round 3
// 612.271 us; speedup vs baseline: 1.7514x; 1.7514x over previous
//
#include <hip/hip_runtime.h>
#include <math.h>

#define BB 4
#define NN 4096
#define KK 16
#define CIN 32
#define COUT 64
#define BN_INV 0.9999950000375f

#define RS 8     // candidate ranges per query
#define PCH 512  // candidates per range (NN/RS)
#define PK 16    // prefilter top-K per range
#define NK2 20   // fp32-selected candidates sent to fp64 rerank

// ---------------- P0: derived W1 weights ----------------
__global__ void p0_weights(const float* __restrict__ W1,
                           float* __restrict__ Aw, float* __restrict__ Bw,
                           float* __restrict__ w1d) {
    int t = threadIdx.x;
    for (int i = t; i < 64 * 32; i += 256) {
        int o = i >> 5, c = i & 31;
        Aw[i] = W1[o * 128 + c] - W1[o * 128 + 64 + c];
        Bw[i] = W1[o * 128 + 32 + c] + W1[o * 128 + 64 + c];
    }
    if (t < 64) {
        float s = 0.f;
        for (int c = 96; c < 128; ++c) s += W1[t * 128 + c];
        w1d[t] = s;
    }
}

// ---------------- P1: transpose features to [B,N,32] + fp32/fp64 norms ----------------
__global__ void p1_transpose(const float* __restrict__ f, float* __restrict__ pT,
                             float* __restrict__ sq32, double* __restrict__ sq64) {
    int g = blockIdx.x * 256 + threadIdx.x;  // b*N + n
    int b = g >> 12, n = g & (NN - 1);
    float v[CIN];
#pragma unroll
    for (int c = 0; c < CIN; ++c) v[c] = f[(b * CIN + c) * NN + n];
#pragma unroll
    for (int c = 0; c < CIN; ++c) pT[(size_t)g * CIN + c] = v[c];
    float s32 = 0.f;
#pragma unroll
    for (int c = 0; c < CIN; ++c) s32 = fmaf(v[c], v[c], s32);  // matches prefilter dot chain
    double s64 = 0.0;
#pragma unroll
    for (int c = 0; c < CIN; ++c) s64 = fma((double)v[c], (double)v[c], s64);  // matches rerank chain
    sq32[g] = s32;
    sq64[g] = s64;
}

// ---------------- P2: per-point projections ctrA = A*p, nbrB = B*p ----------------
__global__ __launch_bounds__(256) void p2_proj(const float* __restrict__ pT,
                                               const float* __restrict__ Aw,
                                               const float* __restrict__ Bw,
                                               float* __restrict__ ctrA,
                                               float* __restrict__ nbrB) {
    __shared__ float sA[32 * 64], sB[32 * 64];
    for (int i = threadIdx.x; i < 2048; i += 256) {
        int o = i >> 5, c = i & 31;
        sA[c * 64 + o] = Aw[i];
        sB[c * 64 + o] = Bw[i];
    }
    __syncthreads();
    int g = blockIdx.x * 256 + threadIdx.x;  // (b*N+n)*64 + o
    int o = g & 63;
    int pn = g >> 6;
    const float* p = pT + (size_t)pn * 32;
    float a = 0.f, bb = 0.f;
#pragma unroll
    for (int c = 0; c < 32; ++c) {
        float pv = p[c];
        a = fmaf(sA[c * 64 + o], pv, a);
        bb = fmaf(sB[c * 64 + o], pv, bb);
    }
    ctrA[g] = a;
    nbrB[g] = bb;
}

// ---------------- KNN prefilter: fp32 top-16 per (query, range) ----------------
// one query per thread; candidate row addresses are wave-uniform -> scalar loads, no LDS
__global__ __launch_bounds__(256) void knn_prefilter(const float* __restrict__ pT,
                                                     const float* __restrict__ sq32,
                                                     float* __restrict__ pval,
                                                     int* __restrict__ pidx) {
    int n = blockIdx.x * 256 + threadIdx.x;  // global point id (b*N+nb)
    int b = n >> 12;
    const float* pb = pT + ((size_t)(b << 12)) * 32;
    const float* sqb = sq32 + (b << 12);
    float qv[32];
    const float4* q4 = (const float4*)(pT + (size_t)n * 32);
#pragma unroll
    for (int c4 = 0; c4 < 8; ++c4) {
        float4 t = q4[c4];
        qv[4 * c4] = t.x; qv[4 * c4 + 1] = t.y; qv[4 * c4 + 2] = t.z; qv[4 * c4 + 3] = t.w;
    }
    float sqn = sq32[n];
    float val[PK];
    int idx[PK];
#pragma unroll
    for (int i = 0; i < PK; ++i) { val[i] = -1e30f; idx[i] = 0; }
    int m0 = blockIdx.y * PCH;
#pragma unroll 2
    for (int mm = 0; mm < PCH; ++mm) {
        int m = m0 + mm;  // wave-uniform
        const float4* row = (const float4*)(pb + (size_t)m * 32);
        float dot = 0.f;
#pragma unroll
        for (int c4 = 0; c4 < 8; ++c4) {
            float4 t = row[c4];
            dot = fmaf(t.x, qv[4 * c4], dot);
            dot = fmaf(t.y, qv[4 * c4 + 1], dot);
            dot = fmaf(t.z, qv[4 * c4 + 2], dot);
            dot = fmaf(t.w, qv[4 * c4 + 3], dot);
        }
        float d = 2.f * dot - sqn - sqb[m];  // self -> exactly 0 (identical chains)
        if (d > val[PK - 1]) {
            float cv = d; int ci = m;
#pragma unroll
            for (int j = 0; j < PK; ++j) {
                bool c = cv > val[j];
                float nv = c ? cv : val[j]; float nc = c ? val[j] : cv;
                int ni = c ? ci : idx[j];   int nj = c ? idx[j] : ci;
                val[j] = nv; cv = nc; idx[j] = ni; ci = nj;
            }
        }
    }
    // layout [r][k][B*N] for coalesced read in knn_final
    size_t base = (size_t)blockIdx.y * PK * (BB * NN) + n;
#pragma unroll
    for (int i = 0; i < PK; ++i) {
        pval[base + (size_t)i * (BB * NN)] = val[i];
        pidx[base + (size_t)i * (BB * NN)] = idx[i];
    }
}

// ---------------- KNN final: fp32 select top-20, fp64 exact rerank -> top-16 ----------------
__global__ __launch_bounds__(256) void knn_final(const float* __restrict__ pT,
                                                 const double* __restrict__ sq64,
                                                 const float* __restrict__ pval,
                                                 const int* __restrict__ pidx,
                                                 int* __restrict__ fidx,
                                                 float* __restrict__ fdist) {
    int n = blockIdx.x * 256 + threadIdx.x;
    int b = n >> 12;
    const float* pb = pT + ((size_t)(b << 12)) * 32;
    const double* sqb = sq64 + (b << 12);

    // fp32 select top-NK2 of RS*PK candidates (strict >, order r-major = idx-asc on ties)
    float sval[NK2];
    int sidx[NK2];
#pragma unroll
    for (int i = 0; i < NK2; ++i) { sval[i] = -1e30f; sidx[i] = 0; }
    for (int u = 0; u < RS * PK; ++u) {
        float cv = pval[(size_t)u * (BB * NN) + n];  // coalesced
        int ci = pidx[(size_t)u * (BB * NN) + n];
        if (cv > sval[NK2 - 1]) {
#pragma unroll
            for (int j = 0; j < NK2; ++j) {
                bool c = cv > sval[j];
                float nv = c ? cv : sval[j]; float nc = c ? sval[j] : cv;
                int ni = c ? ci : sidx[j];   int nj = c ? sidx[j] : ci;
                sval[j] = nv; cv = nc; sidx[j] = ni; ci = nj;
            }
        }
    }

    // fp64 exact rerank of the NK2 survivors (chains identical to R2's passing kernel)
    double qv[32];
    const float4* q4 = (const float4*)(pT + (size_t)n * 32);
#pragma unroll
    for (int c4 = 0; c4 < 8; ++c4) {
        float4 t = q4[c4];
        qv[4 * c4] = (double)t.x; qv[4 * c4 + 1] = (double)t.y;
        qv[4 * c4 + 2] = (double)t.z; qv[4 * c4 + 3] = (double)t.w;
    }
    double sqn = 0.0;
#pragma unroll
    for (int c = 0; c < 32; ++c) sqn = fma(qv[c], qv[c], sqn);

    double dv[16];
    int di[16];
#pragma unroll
    for (int i = 0; i < 16; ++i) { dv[i] = -1e300; di[i] = 0x7fffffff; }
#pragma unroll
    for (int u = 0; u < NK2; ++u) {
        int m = sidx[u];
        const float4* row = (const float4*)(pb + (size_t)m * 32);
        double dot = 0.0;
#pragma unroll
        for (int c4 = 0; c4 < 8; ++c4) {
            float4 t = row[c4];
            dot = fma((double)t.x, qv[4 * c4], dot);
            dot = fma((double)t.y, qv[4 * c4 + 1], dot);
            dot = fma((double)t.z, qv[4 * c4 + 2], dot);
            dot = fma((double)t.w, qv[4 * c4 + 3], dot);
        }
        double d = 2.0 * dot - sqn - sqb[m];  // self -> exactly 0
        if (d > dv[15] || (d == dv[15] && m < di[15])) {
            double cv = d; int ci = m;
#pragma unroll
            for (int j = 0; j < 16; ++j) {
                bool c = (cv > dv[j]) || (cv == dv[j] && ci < di[j]);
                double nv = c ? cv : dv[j]; double nc = c ? dv[j] : cv;
                int ni = c ? ci : di[j];    int nj = c ? di[j] : ci;
                dv[j] = nv; cv = nc; di[j] = ni; ci = nj;
            }
        }
    }
#pragma unroll
    for (int i = 0; i < 16; ++i) {
        fdist[(size_t)n * 16 + i] = (float)dv[i];
        fidx[(size_t)n * 16 + i] = di[i];
    }
}

// ---------------- Fused main pipeline: one thread per (b,n,k) ----------------
__global__ __launch_bounds__(256) void fuse_kernel(
    const float* __restrict__ coords, const float* __restrict__ feat,
    const int* __restrict__ knn_idx, const float* __restrict__ knn_dist,
    const float* __restrict__ W2, const float* __restrict__ W3,
    const float* __restrict__ W4, const float* __restrict__ W5,
    const float* __restrict__ g1, const float* __restrict__ b1,
    const float* __restrict__ g2, const float* __restrict__ b2,
    const float* __restrict__ g3, const float* __restrict__ b3,
    const float* __restrict__ g4, const float* __restrict__ b4,
    const float* __restrict__ g5, const float* __restrict__ b5,
    const float* __restrict__ ctrA, const float* __restrict__ nbrB,
    const float* __restrict__ w1d, const int* __restrict__ fidx,
    const float* __restrict__ fdist, float* __restrict__ out) {
    int g = blockIdx.x * 256 + threadIdx.x;
    int k = g & 15;
    int n = (g >> 4) & (NN - 1);
    int b = g >> 16;
    int pn = b * NN + n;

    int fnb = fidx[(size_t)pn * 16 + k];
    float fd = fdist[(size_t)pn * 16 + k];
    const float* cA = ctrA + (size_t)pn * 64;
    const float* nB = nbrB + ((size_t)b * NN + fnb) * 64;

    float fk[64];
#pragma unroll
    for (int o = 0; o < 64; ++o) {
        float y = cA[o] + nB[o] + w1d[o] * fd;
        float v = fmaf(g1[o] * BN_INV, y, b1[o]);
        fk[o] = v > 0.f ? v : 0.2f * v;
    }

    float cq[3], cn_[3];
#pragma unroll
    for (int j = 0; j < 3; ++j) cq[j] = coords[(size_t)pn * 3 + j];
    int cnb = knn_idx[(size_t)pn * 16 + k];
#pragma unroll
    for (int j = 0; j < 3; ++j) cn_[j] = coords[((size_t)b * NN + cnb) * 3 + j];
    float kd = knn_dist[(size_t)pn * 16 + k];

    float cp[13];
#pragma unroll
    for (int j = 0; j < 3; ++j) {
        float a = 0.f;
#pragma unroll
        for (int o = 0; o < 64; ++o) a = fmaf(W2[j * 64 + o], fk[o], a);
        float t = fmaf(g2[j] * BN_INV, a, b2[j]);
        t = t > 0.f ? t : expm1f(t);  // elu
        cp[j] = cq[j];
        cp[3 + j] = cn_[j];
        cp[6 + j] = cq[j] - cn_[j];
        cp[10 + j] = t + cq[j];
    }
    cp[9] = kd;

    float fe[32];
#pragma unroll
    for (int c = 0; c < 32; ++c) {
        float a3 = 0.f, a4 = 0.f;
#pragma unroll
        for (int j = 0; j < 13; ++j) {
            a3 = fmaf(W3[c * 13 + j], cp[j], a3);
            a4 = fmaf(W4[c * 13 + j], cp[j], a4);
        }
        float po = fmaf(g3[c] * BN_INV, a3, b3[c]);
        po = po > 0.f ? po : expm1f(po);
        fe[c] = po + feat[(b * 32 + c) * NN + n];
        float op = fmaf(g4[c] * BN_INV, a4, b4[c]);
        op = op > 0.f ? op : expm1f(op);
        out[(((size_t)b * 64 + c) * NN + n) * 16 + k] = op;
    }

#pragma unroll
    for (int c = 0; c < 32; ++c) {
        float a5 = 0.f;
#pragma unroll
        for (int o = 0; o < 64; ++o) a5 = fmaf(W5[c * 96 + o], fk[o], a5);
#pragma unroll
        for (int j = 0; j < 32; ++j) a5 = fmaf(W5[c * 96 + 64 + j], fe[j], a5);
        float v = fmaf(g5[c] * BN_INV, a5, b5[c]);
        v = v > 0.f ? v : expm1f(v);
        out[(((size_t)b * 64 + 32 + c) * NN + n) * 16 + k] = v;
    }
}

extern "C" void kernel_launch(void* const* d_in, const int* in_sizes, int n_in,
                              void* d_out, int out_size, void* d_ws, size_t ws_size,
                              hipStream_t stream) {
    const float* coords   = (const float*)d_in[0];
    const float* features = (const float*)d_in[1];
    const int*   knn_idx  = (const int*)d_in[2];
    const float* knn_dist = (const float*)d_in[3];
    const float* W1 = (const float*)d_in[4];
    const float* W2 = (const float*)d_in[5];
    const float* W3 = (const float*)d_in[6];
    const float* W4 = (const float*)d_in[7];
    const float* W5 = (const float*)d_in[8];
    const float* g1 = (const float*)d_in[9];
    const float* b1 = (const float*)d_in[10];
    const float* g2 = (const float*)d_in[11];
    const float* b2 = (const float*)d_in[12];
    const float* g3 = (const float*)d_in[13];
    const float* b3 = (const float*)d_in[14];
    const float* g4 = (const float*)d_in[15];
    const float* b4 = (const float*)d_in[16];
    const float* g5 = (const float*)d_in[17];
    const float* b5 = (const float*)d_in[18];
    float* out = (float*)d_out;

    // workspace layout (float slots); pval/pidx alias ctrA/nbrB (disjoint lifetimes)
    float*  pT    = (float*)d_ws;                  // 524288
    float*  sq32  = pT + BB * NN * 32;             // 16384
    double* sq64  = (double*)(sq32 + BB * NN);     // 16384 doubles (32768 slots)
    float*  fdist = (float*)(sq64 + BB * NN);      // 262144
    int*    fidx  = (int*)(fdist + BB * NN * 16);  // 262144
    float*  Aw    = (float*)(fidx + BB * NN * 16); // 2048
    float*  Bw    = Aw + 2048;                     // 2048
    float*  w1d   = Bw + 2048;                     // 64
    float*  U     = w1d + 64;                      // union region
    float*  pval  = U;                             // RS*PK*B*N = 2097152
    int*    pidx  = (int*)(U + (size_t)RS * PK * BB * NN);  // 2097152
    float*  ctrA  = U;                             // B*N*64 = 1048576 (after knn done)
    float*  nbrB  = U + BB * NN * 64;              // B*N*64 = 1048576

    hipLaunchKernelGGL(p0_weights, dim3(1), dim3(256), 0, stream, W1, Aw, Bw, w1d);
    hipLaunchKernelGGL(p1_transpose, dim3(BB * NN / 256), dim3(256), 0, stream,
                       features, pT, sq32, sq64);
    hipLaunchKernelGGL(knn_prefilter, dim3(BB * NN / 256, RS), dim3(256), 0, stream,
                       pT, sq32, pval, pidx);
    hipLaunchKernelGGL(knn_final, dim3(BB * NN / 256), dim3(256), 0, stream,
                       pT, sq64, pval, pidx, fidx, fdist);
    hipLaunchKernelGGL(p2_proj, dim3(BB * NN * 64 / 256), dim3(256), 0, stream,
                       pT, Aw, Bw, ctrA, nbrB);
    hipLaunchKernelGGL(fuse_kernel, dim3(BB * NN * KK / 256), dim3(256), 0, stream,
                       coords, features, knn_idx, knn_dist, W2, W3, W4, W5,
                       g1, b1, g2, b2, g3, b3, g4, b4, g5, b5,
                       ctrA, nbrB, w1d, fidx, fdist, out);
}

// Round 4
// 606.792 us; speedup vs baseline: 1.7672x; 1.0090x over previous
//
#include <hip/hip_runtime.h>
#include <math.h>

#define BB 4
#define NN 4096
#define KK 16
#define CIN 32
#define COUT 64
#define BN_INV 0.9999950000375f

#define RS 16    // candidate ranges per query
#define PCH 256  // candidates per range (NN/RS)
#define PK 16    // prefilter top-K per range
#define NK2 24   // candidates sent to fp64 rerank

// ---------------- P0: derived W1 weights ----------------
__global__ void p0_weights(const float* __restrict__ W1,
                           float* __restrict__ Aw, float* __restrict__ Bw,
                           float* __restrict__ w1d) {
    int t = threadIdx.x;
    for (int i = t; i < 64 * 32; i += 256) {
        int o = i >> 5, c = i & 31;
        Aw[i] = W1[o * 128 + c] - W1[o * 128 + 64 + c];
        Bw[i] = W1[o * 128 + 32 + c] + W1[o * 128 + 64 + c];
    }
    if (t < 64) {
        float s = 0.f;
        for (int c = 96; c < 128; ++c) s += W1[t * 128 + c];
        w1d[t] = s;
    }
}

// ---------------- P1: transpose features to [B,N,32] + fp32/fp64 norms ----------------
__global__ void p1_transpose(const float* __restrict__ f, float* __restrict__ pT,
                             float* __restrict__ sq32, double* __restrict__ sq64) {
    int g = blockIdx.x * 256 + threadIdx.x;  // b*N + n
    int b = g >> 12, n = g & (NN - 1);
    float v[CIN];
#pragma unroll
    for (int c = 0; c < CIN; ++c) v[c] = f[(b * CIN + c) * NN + n];
#pragma unroll
    for (int c = 0; c < CIN; ++c) pT[(size_t)g * CIN + c] = v[c];
    float s32 = 0.f;
#pragma unroll
    for (int c = 0; c < CIN; ++c) s32 = fmaf(v[c], v[c], s32);  // matches prefilter dot chain
    double s64 = 0.0;
#pragma unroll
    for (int c = 0; c < CIN; ++c) s64 = fma((double)v[c], (double)v[c], s64);  // matches rerank chain
    sq32[g] = s32;
    sq64[g] = s64;
}

// ---------------- P2: per-point projections ctrA = A*p, nbrB = B*p ----------------
__global__ __launch_bounds__(256) void p2_proj(const float* __restrict__ pT,
                                               const float* __restrict__ Aw,
                                               const float* __restrict__ Bw,
                                               float* __restrict__ ctrA,
                                               float* __restrict__ nbrB) {
    __shared__ float sA[32 * 64], sB[32 * 64];
    for (int i = threadIdx.x; i < 2048; i += 256) {
        int o = i >> 5, c = i & 31;
        sA[c * 64 + o] = Aw[i];
        sB[c * 64 + o] = Bw[i];
    }
    __syncthreads();
    int g = blockIdx.x * 256 + threadIdx.x;  // (b*N+n)*64 + o
    int o = g & 63;
    int pn = g >> 6;
    const float* p = pT + (size_t)pn * 32;
    float a = 0.f, bb = 0.f;
#pragma unroll
    for (int c = 0; c < 32; ++c) {
        float pv = p[c];
        a = fmaf(sA[c * 64 + o], pv, a);
        bb = fmaf(sB[c * 64 + o], pv, bb);
    }
    ctrA[g] = a;
    nbrB[g] = bb;
}

// ---------------- KNN prefilter: branchless packed-key top-16 per (query, range) ----
// key = monotone(f32 dist) top-20-bits | (4095 - m); insert = 2 VALU/step min/max chain
__global__ __launch_bounds__(256) void knn_prefilter(const float* __restrict__ pT,
                                                     const float* __restrict__ sq32,
                                                     unsigned* __restrict__ pkey) {
    int n = blockIdx.x * 256 + threadIdx.x;  // global point id (b*N+nb)
    int b = n >> 12;
    const float* pb = pT + ((size_t)(b << 12)) * 32;
    const float* sqb = sq32 + (b << 12);
    float qv[32];
    const float4* q4 = (const float4*)(pT + (size_t)n * 32);
#pragma unroll
    for (int c4 = 0; c4 < 8; ++c4) {
        float4 t = q4[c4];
        qv[4 * c4] = t.x; qv[4 * c4 + 1] = t.y; qv[4 * c4 + 2] = t.z; qv[4 * c4 + 3] = t.w;
    }
    float negsqn = -sq32[n];
    unsigned key[PK];
#pragma unroll
    for (int i = 0; i < PK; ++i) key[i] = 0u;
    int m0 = blockIdx.y * PCH;
#pragma unroll 2
    for (int mm = 0; mm < PCH; ++mm) {
        int m = m0 + mm;  // wave-uniform
        const float4* row = (const float4*)(pb + (size_t)m * 32);
        float dot = 0.f;
#pragma unroll
        for (int c4 = 0; c4 < 8; ++c4) {
            float4 t = row[c4];
            dot = fmaf(t.x, qv[4 * c4], dot);
            dot = fmaf(t.y, qv[4 * c4 + 1], dot);
            dot = fmaf(t.z, qv[4 * c4 + 2], dot);
            dot = fmaf(t.w, qv[4 * c4 + 3], dot);
        }
        // self: dot == sqn bitwise (identical chain), negsqn - sqn = -2*sqn exact,
        // fmaf(2,dot,-2*sqn) == 0 exactly -> top key
        float d = fmaf(2.f, dot, negsqn - sqb[m]);
        unsigned u = __float_as_uint(d);
        unsigned k32 = u ^ (unsigned)(((int)u >> 31) | 0x80000000);
        unsigned cv = (k32 & 0xFFFFF000u) | (unsigned)(4095 - m);
        // branchless 16-deep sorted insert: 2 VALU per step
#pragma unroll
        for (int j = 0; j < PK; ++j) {
            unsigned vj = key[j];
            unsigned hi = cv > vj ? cv : vj;
            unsigned lo = cv > vj ? vj : cv;
            key[j] = hi; cv = lo;
        }
    }
    // layout [r][k][B*N] for coalesced read in knn_final
    size_t base = (size_t)blockIdx.y * PK * (BB * NN) + n;
#pragma unroll
    for (int i = 0; i < PK; ++i) pkey[base + (size_t)i * (BB * NN)] = key[i];
}

// ---------------- KNN final: key-select top-24, fp64 exact rerank -> top-16 ----------------
__global__ __launch_bounds__(256) void knn_final(const float* __restrict__ pT,
                                                 const double* __restrict__ sq64,
                                                 const unsigned* __restrict__ pkey,
                                                 int* __restrict__ fidx,
                                                 float* __restrict__ fdist) {
    int n = blockIdx.x * 256 + threadIdx.x;
    int b = n >> 12;
    const float* pb = pT + ((size_t)(b << 12)) * 32;
    const double* sqb = sq64 + (b << 12);

    // select top-NK2 keys of RS*PK candidates (branchless min/max chain)
    unsigned sk[NK2];
#pragma unroll
    for (int i = 0; i < NK2; ++i) sk[i] = 0u;
    for (int u = 0; u < RS * PK; ++u) {
        unsigned cv = pkey[(size_t)u * (BB * NN) + n];  // coalesced
#pragma unroll
        for (int j = 0; j < NK2; ++j) {
            unsigned vj = sk[j];
            unsigned hi = cv > vj ? cv : vj;
            unsigned lo = cv > vj ? vj : cv;
            sk[j] = hi; cv = lo;
        }
    }

    // fp64 exact rerank of the NK2 survivors (chains identical to R2's passing kernel)
    double qv[32];
    const float4* q4 = (const float4*)(pT + (size_t)n * 32);
#pragma unroll
    for (int c4 = 0; c4 < 8; ++c4) {
        float4 t = q4[c4];
        qv[4 * c4] = (double)t.x; qv[4 * c4 + 1] = (double)t.y;
        qv[4 * c4 + 2] = (double)t.z; qv[4 * c4 + 3] = (double)t.w;
    }
    double sqn = 0.0;
#pragma unroll
    for (int c = 0; c < 32; ++c) sqn = fma(qv[c], qv[c], sqn);

    double dv[16];
    int di[16];
#pragma unroll
    for (int i = 0; i < 16; ++i) { dv[i] = -1e300; di[i] = 0x7fffffff; }
#pragma unroll
    for (int u = 0; u < NK2; ++u) {
        int m = 4095 - (int)(sk[u] & 0xFFFu);
        const float4* row = (const float4*)(pb + (size_t)m * 32);
        double dot = 0.0;
#pragma unroll
        for (int c4 = 0; c4 < 8; ++c4) {
            float4 t = row[c4];
            dot = fma((double)t.x, qv[4 * c4], dot);
            dot = fma((double)t.y, qv[4 * c4 + 1], dot);
            dot = fma((double)t.z, qv[4 * c4 + 2], dot);
            dot = fma((double)t.w, qv[4 * c4 + 3], dot);
        }
        double d = 2.0 * dot - sqn - sqb[m];  // self -> exactly 0
        if (d > dv[15] || (d == dv[15] && m < di[15])) {
            double cv = d; int ci = m;
#pragma unroll
            for (int j = 0; j < 16; ++j) {
                bool c = (cv > dv[j]) || (cv == dv[j] && ci < di[j]);
                double nv = c ? cv : dv[j]; double nc = c ? dv[j] : cv;
                int ni = c ? ci : di[j];    int nj = c ? di[j] : ci;
                dv[j] = nv; cv = nc; di[j] = ni; ci = nj;
            }
        }
    }
#pragma unroll
    for (int i = 0; i < 16; ++i) {
        fdist[(size_t)n * 16 + i] = (float)dv[i];
        fidx[(size_t)n * 16 + i] = di[i];
    }
}

// ---------------- Fused main pipeline: one thread per (b,n,k) ----------------
__global__ __launch_bounds__(256) void fuse_kernel(
    const float* __restrict__ coords, const float* __restrict__ feat,
    const int* __restrict__ knn_idx, const float* __restrict__ knn_dist,
    const float* __restrict__ W2, const float* __restrict__ W3,
    const float* __restrict__ W4, const float* __restrict__ W5,
    const float* __restrict__ g1, const float* __restrict__ b1,
    const float* __restrict__ g2, const float* __restrict__ b2,
    const float* __restrict__ g3, const float* __restrict__ b3,
    const float* __restrict__ g4, const float* __restrict__ b4,
    const float* __restrict__ g5, const float* __restrict__ b5,
    const float* __restrict__ ctrA, const float* __restrict__ nbrB,
    const float* __restrict__ w1d, const int* __restrict__ fidx,
    const float* __restrict__ fdist, float* __restrict__ out) {
    int g = blockIdx.x * 256 + threadIdx.x;
    int k = g & 15;
    int n = (g >> 4) & (NN - 1);
    int b = g >> 16;
    int pn = b * NN + n;

    int fnb = fidx[(size_t)pn * 16 + k];
    float fd = fdist[(size_t)pn * 16 + k];
    const float* cA = ctrA + (size_t)pn * 64;
    const float* nB = nbrB + ((size_t)b * NN + fnb) * 64;

    float fk[64];
#pragma unroll
    for (int o = 0; o < 64; ++o) {
        float y = cA[o] + nB[o] + w1d[o] * fd;
        float v = fmaf(g1[o] * BN_INV, y, b1[o]);
        fk[o] = v > 0.f ? v : 0.2f * v;
    }

    float cq[3], cn_[3];
#pragma unroll
    for (int j = 0; j < 3; ++j) cq[j] = coords[(size_t)pn * 3 + j];
    int cnb = knn_idx[(size_t)pn * 16 + k];
#pragma unroll
    for (int j = 0; j < 3; ++j) cn_[j] = coords[((size_t)b * NN + cnb) * 3 + j];
    float kd = knn_dist[(size_t)pn * 16 + k];

    float cp[13];
#pragma unroll
    for (int j = 0; j < 3; ++j) {
        float a = 0.f;
#pragma unroll
        for (int o = 0; o < 64; ++o) a = fmaf(W2[j * 64 + o], fk[o], a);
        float t = fmaf(g2[j] * BN_INV, a, b2[j]);
        t = t > 0.f ? t : expm1f(t);  // elu
        cp[j] = cq[j];
        cp[3 + j] = cn_[j];
        cp[6 + j] = cq[j] - cn_[j];
        cp[10 + j] = t + cq[j];
    }
    cp[9] = kd;

    float fe[32];
#pragma unroll
    for (int c = 0; c < 32; ++c) {
        float a3 = 0.f, a4 = 0.f;
#pragma unroll
        for (int j = 0; j < 13; ++j) {
            a3 = fmaf(W3[c * 13 + j], cp[j], a3);
            a4 = fmaf(W4[c * 13 + j], cp[j], a4);
        }
        float po = fmaf(g3[c] * BN_INV, a3, b3[c]);
        po = po > 0.f ? po : expm1f(po);
        fe[c] = po + feat[(b * 32 + c) * NN + n];
        float op = fmaf(g4[c] * BN_INV, a4, b4[c]);
        op = op > 0.f ? op : expm1f(op);
        out[(((size_t)b * 64 + c) * NN + n) * 16 + k] = op;
    }

#pragma unroll
    for (int c = 0; c < 32; ++c) {
        float a5 = 0.f;
#pragma unroll
        for (int o = 0; o < 64; ++o) a5 = fmaf(W5[c * 96 + o], fk[o], a5);
#pragma unroll
        for (int j = 0; j < 32; ++j) a5 = fmaf(W5[c * 96 + 64 + j], fe[j], a5);
        float v = fmaf(g5[c] * BN_INV, a5, b5[c]);
        v = v > 0.f ? v : expm1f(v);
        out[(((size_t)b * 64 + 32 + c) * NN + n) * 16 + k] = v;
    }
}

extern "C" void kernel_launch(void* const* d_in, const int* in_sizes, int n_in,
                              void* d_out, int out_size, void* d_ws, size_t ws_size,
                              hipStream_t stream) {
    const float* coords   = (const float*)d_in[0];
    const float* features = (const float*)d_in[1];
    const int*   knn_idx  = (const int*)d_in[2];
    const float* knn_dist = (const float*)d_in[3];
    const float* W1 = (const float*)d_in[4];
    const float* W2 = (const float*)d_in[5];
    const float* W3 = (const float*)d_in[6];
    const float* W4 = (const float*)d_in[7];
    const float* W5 = (const float*)d_in[8];
    const float* g1 = (const float*)d_in[9];
    const float* b1 = (const float*)d_in[10];
    const float* g2 = (const float*)d_in[11];
    const float* b2 = (const float*)d_in[12];
    const float* g3 = (const float*)d_in[13];
    const float* b3 = (const float*)d_in[14];
    const float* g4 = (const float*)d_in[15];
    const float* b4 = (const float*)d_in[16];
    const float* g5 = (const float*)d_in[17];
    const float* b5 = (const float*)d_in[18];
    float* out = (float*)d_out;

    // workspace layout (float slots); pkey aliases ctrA/nbrB (disjoint lifetimes)
    float*  pT    = (float*)d_ws;                  // 524288
    float*  sq32  = pT + BB * NN * 32;             // 16384
    double* sq64  = (double*)(sq32 + BB * NN);     // 16384 doubles (32768 slots)
    float*  fdist = (float*)(sq64 + BB * NN);      // 262144
    int*    fidx  = (int*)(fdist + BB * NN * 16);  // 262144
    float*  Aw    = (float*)(fidx + BB * NN * 16); // 2048
    float*  Bw    = Aw + 2048;                     // 2048
    float*  w1d   = Bw + 2048;                     // 64
    float*  U     = w1d + 64;                      // union region
    unsigned* pkey = (unsigned*)U;                 // RS*PK*B*N = 4194304 u32
    float*  ctrA  = U;                             // B*N*64 (after knn done)
    float*  nbrB  = U + BB * NN * 64;              // B*N*64

    hipLaunchKernelGGL(p0_weights, dim3(1), dim3(256), 0, stream, W1, Aw, Bw, w1d);
    hipLaunchKernelGGL(p1_transpose, dim3(BB * NN / 256), dim3(256), 0, stream,
                       features, pT, sq32, sq64);
    hipLaunchKernelGGL(knn_prefilter, dim3(BB * NN / 256, RS), dim3(256), 0, stream,
                       pT, sq32, pkey);
    hipLaunchKernelGGL(knn_final, dim3(BB * NN / 256), dim3(256), 0, stream,
                       pT, sq64, pkey, fidx, fdist);
    hipLaunchKernelGGL(p2_proj, dim3(BB * NN * 64 / 256), dim3(256), 0, stream,
                       pT, Aw, Bw, ctrA, nbrB);
    hipLaunchKernelGGL(fuse_kernel, dim3(BB * NN * KK / 256), dim3(256), 0, stream,
                       coords, features, knn_idx, knn_dist, W2, W3, W4, W5,
                       g1, b1, g2, b2, g3, b3, g4, b4, g5, b5,
                       ctrA, nbrB, w1d, fidx, fdist, out);
}

// Round 5
// 540.161 us; speedup vs baseline: 1.9852x; 1.1234x over previous
//
#include <hip/hip_runtime.h>
#include <math.h>

#define BB 4
#define NN 4096
#define KK 16
#define CIN 32
#define COUT 64
#define BN_INV 0.9999950000375f

#define RS 32    // candidate ranges per query
#define PCH 128  // candidates per range (NN/RS)
#define PK 16    // prefilter top-K per range
#define NK2 24   // candidates sent to fp64 rerank

// ---------------- P0: derived W1 weights ----------------
__global__ void p0_weights(const float* __restrict__ W1,
                           float* __restrict__ Aw, float* __restrict__ Bw,
                           float* __restrict__ w1d) {
    int t = threadIdx.x;
    for (int i = t; i < 64 * 32; i += 256) {
        int o = i >> 5, c = i & 31;
        Aw[i] = W1[o * 128 + c] - W1[o * 128 + 64 + c];
        Bw[i] = W1[o * 128 + 32 + c] + W1[o * 128 + 64 + c];
    }
    if (t < 64) {
        float s = 0.f;
        for (int c = 96; c < 128; ++c) s += W1[t * 128 + c];
        w1d[t] = s;
    }
}

// ---------------- P1: transpose features to [B,N,32] + fp32/fp64 norms ----------------
__global__ void p1_transpose(const float* __restrict__ f, float* __restrict__ pT,
                             float* __restrict__ sq32, double* __restrict__ sq64) {
    int g = blockIdx.x * 256 + threadIdx.x;  // b*N + n
    int b = g >> 12, n = g & (NN - 1);
    float v[CIN];
#pragma unroll
    for (int c = 0; c < CIN; ++c) v[c] = f[(b * CIN + c) * NN + n];
#pragma unroll
    for (int c = 0; c < CIN; ++c) pT[(size_t)g * CIN + c] = v[c];
    // 4-accumulator chain — must be BITWISE identical to knn_prefilter's dot chain
    float a0 = 0.f, a1 = 0.f, a2 = 0.f, a3 = 0.f;
#pragma unroll
    for (int c4 = 0; c4 < 8; ++c4) {
        a0 = fmaf(v[4 * c4 + 0], v[4 * c4 + 0], a0);
        a1 = fmaf(v[4 * c4 + 1], v[4 * c4 + 1], a1);
        a2 = fmaf(v[4 * c4 + 2], v[4 * c4 + 2], a2);
        a3 = fmaf(v[4 * c4 + 3], v[4 * c4 + 3], a3);
    }
    sq32[g] = (a0 + a1) + (a2 + a3);
    // sequential fp64 chain — must match knn_final's rerank chains
    double s64 = 0.0;
#pragma unroll
    for (int c = 0; c < CIN; ++c) s64 = fma((double)v[c], (double)v[c], s64);
    sq64[g] = s64;
}

// ---------------- P2: per-point projections ctrA = A*p, nbrB = B*p ----------------
__global__ __launch_bounds__(256) void p2_proj(const float* __restrict__ pT,
                                               const float* __restrict__ Aw,
                                               const float* __restrict__ Bw,
                                               float* __restrict__ ctrA,
                                               float* __restrict__ nbrB) {
    __shared__ float sA[32 * 64], sB[32 * 64];
    for (int i = threadIdx.x; i < 2048; i += 256) {
        int o = i >> 5, c = i & 31;
        sA[c * 64 + o] = Aw[i];
        sB[c * 64 + o] = Bw[i];
    }
    __syncthreads();
    int g = blockIdx.x * 256 + threadIdx.x;  // (b*N+n)*64 + o
    int o = g & 63;
    int pn = g >> 6;
    const float* p = pT + (size_t)pn * 32;
    float a = 0.f, bb = 0.f;
#pragma unroll
    for (int c = 0; c < 32; ++c) {
        float pv = p[c];
        a = fmaf(sA[c * 64 + o], pv, a);
        bb = fmaf(sB[c * 64 + o], pv, bb);
    }
    ctrA[g] = a;
    nbrB[g] = bb;
}

// ---------------- KNN prefilter: branchless packed-key top-16 per (query, range) ----
__global__ __launch_bounds__(256) void knn_prefilter(const float* __restrict__ pT,
                                                     const float* __restrict__ sq32,
                                                     unsigned* __restrict__ pkey) {
    int n = blockIdx.x * 256 + threadIdx.x;  // global point id (b*N+nb)
    int b = n >> 12;
    const float* pb = pT + ((size_t)(b << 12)) * 32;
    const float* sqb = sq32 + (b << 12);
    float qv[32];
    const float4* q4 = (const float4*)(pT + (size_t)n * 32);
#pragma unroll
    for (int c4 = 0; c4 < 8; ++c4) {
        float4 t = q4[c4];
        qv[4 * c4] = t.x; qv[4 * c4 + 1] = t.y; qv[4 * c4 + 2] = t.z; qv[4 * c4 + 3] = t.w;
    }
    float negsqn = -sq32[n];
    unsigned key[PK];
#pragma unroll
    for (int i = 0; i < PK; ++i) key[i] = 0u;
    int m0 = blockIdx.y * PCH;
#pragma unroll 2
    for (int mm = 0; mm < PCH; ++mm) {
        int m = m0 + mm;  // wave-uniform
        const float4* row = (const float4*)(pb + (size_t)m * 32);
        float a0 = 0.f, a1 = 0.f, a2 = 0.f, a3 = 0.f;
#pragma unroll
        for (int c4 = 0; c4 < 8; ++c4) {
            float4 t = row[c4];
            a0 = fmaf(t.x, qv[4 * c4 + 0], a0);
            a1 = fmaf(t.y, qv[4 * c4 + 1], a1);
            a2 = fmaf(t.z, qv[4 * c4 + 2], a2);
            a3 = fmaf(t.w, qv[4 * c4 + 3], a3);
        }
        float dot = (a0 + a1) + (a2 + a3);
        // self: dot == sqn bitwise (identical chain), fmaf(2,dot,-2*sqn) == 0 exactly
        float d = fmaf(2.f, dot, negsqn - sqb[m]);
        unsigned u = __float_as_uint(d);
        unsigned k32 = u ^ (unsigned)(((int)u >> 31) | 0x80000000);
        unsigned cv = (k32 & 0xFFFFF000u) | (unsigned)(4095 - m);
        // branchless 16-deep sorted insert: 2 VALU per step
#pragma unroll
        for (int j = 0; j < PK; ++j) {
            unsigned vj = key[j];
            unsigned hi = cv > vj ? cv : vj;
            unsigned lo = cv > vj ? vj : cv;
            key[j] = hi; cv = lo;
        }
    }
    // layout [r][k][B*N] for coalesced read in knn_final
    size_t base = (size_t)blockIdx.y * PK * (BB * NN) + n;
#pragma unroll
    for (int i = 0; i < PK; ++i) pkey[base + (size_t)i * (BB * NN)] = key[i];
}

// ---------------- KNN final: key-select top-24, fp64 exact rerank -> top-16 ----------------
__global__ __launch_bounds__(64) void knn_final(const float* __restrict__ pT,
                                                const double* __restrict__ sq64,
                                                const unsigned* __restrict__ pkey,
                                                int* __restrict__ fidx,
                                                float* __restrict__ fdist) {
    int n = blockIdx.x * 64 + threadIdx.x;
    int b = n >> 12;
    const float* pb = pT + ((size_t)(b << 12)) * 32;
    const double* sqb = sq64 + (b << 12);

    // select top-NK2 keys of RS*PK candidates; per-range keys arrive sorted desc,
    // so once no lane in the wave can insert, the rest of the range is skippable.
    unsigned sk[NK2];
#pragma unroll
    for (int i = 0; i < NK2; ++i) sk[i] = 0u;
    for (int r = 0; r < RS; ++r) {
        unsigned kv[PK];
#pragma unroll
        for (int k = 0; k < PK; ++k)
            kv[k] = pkey[(size_t)(r * PK + k) * (BB * NN) + n];  // coalesced batch
        for (int k = 0; k < PK; ++k) {
            unsigned cv = kv[k];
            if (__all(cv <= sk[NK2 - 1])) break;  // lane-keys descend within range
#pragma unroll
            for (int j = 0; j < NK2; ++j) {
                unsigned vj = sk[j];
                unsigned hi = cv > vj ? cv : vj;
                unsigned lo = cv > vj ? vj : cv;
                sk[j] = hi; cv = lo;
            }
        }
    }

    // fp64 exact rerank of the NK2 survivors (chains identical to R2's passing kernel)
    double qv[32];
    const float4* q4 = (const float4*)(pT + (size_t)n * 32);
#pragma unroll
    for (int c4 = 0; c4 < 8; ++c4) {
        float4 t = q4[c4];
        qv[4 * c4] = (double)t.x; qv[4 * c4 + 1] = (double)t.y;
        qv[4 * c4 + 2] = (double)t.z; qv[4 * c4 + 3] = (double)t.w;
    }
    double sqn = 0.0;
#pragma unroll
    for (int c = 0; c < 32; ++c) sqn = fma(qv[c], qv[c], sqn);

    double dv[16];
    int di[16];
#pragma unroll
    for (int i = 0; i < 16; ++i) { dv[i] = -1e300; di[i] = 0x7fffffff; }
#pragma unroll
    for (int u = 0; u < NK2; ++u) {
        int m = 4095 - (int)(sk[u] & 0xFFFu);
        const float4* row = (const float4*)(pb + (size_t)m * 32);
        double dot = 0.0;
#pragma unroll
        for (int c4 = 0; c4 < 8; ++c4) {
            float4 t = row[c4];
            dot = fma((double)t.x, qv[4 * c4], dot);
            dot = fma((double)t.y, qv[4 * c4 + 1], dot);
            dot = fma((double)t.z, qv[4 * c4 + 2], dot);
            dot = fma((double)t.w, qv[4 * c4 + 3], dot);
        }
        double d = 2.0 * dot - sqn - sqb[m];  // self -> exactly 0
        if (d > dv[15] || (d == dv[15] && m < di[15])) {
            double cv = d; int ci = m;
#pragma unroll
            for (int j = 0; j < 16; ++j) {
                bool c = (cv > dv[j]) || (cv == dv[j] && ci < di[j]);
                double nv = c ? cv : dv[j]; double nc = c ? dv[j] : cv;
                int ni = c ? ci : di[j];    int nj = c ? di[j] : ci;
                dv[j] = nv; cv = nc; di[j] = ni; ci = nj;
            }
        }
    }
#pragma unroll
    for (int i = 0; i < 16; ++i) {
        fdist[(size_t)n * 16 + i] = (float)dv[i];
        fidx[(size_t)n * 16 + i] = di[i];
    }
}

// ---------------- Fused main pipeline: one thread per (b,n,k) ----------------
__global__ __launch_bounds__(256) void fuse_kernel(
    const float* __restrict__ coords, const float* __restrict__ feat,
    const int* __restrict__ knn_idx, const float* __restrict__ knn_dist,
    const float* __restrict__ W2, const float* __restrict__ W3,
    const float* __restrict__ W4, const float* __restrict__ W5,
    const float* __restrict__ g1, const float* __restrict__ b1,
    const float* __restrict__ g2, const float* __restrict__ b2,
    const float* __restrict__ g3, const float* __restrict__ b3,
    const float* __restrict__ g4, const float* __restrict__ b4,
    const float* __restrict__ g5, const float* __restrict__ b5,
    const float* __restrict__ ctrA, const float* __restrict__ nbrB,
    const float* __restrict__ w1d, const int* __restrict__ fidx,
    const float* __restrict__ fdist, float* __restrict__ out) {
    int g = blockIdx.x * 256 + threadIdx.x;
    int k = g & 15;
    int n = (g >> 4) & (NN - 1);
    int b = g >> 16;
    int pn = b * NN + n;

    int fnb = fidx[(size_t)pn * 16 + k];
    float fd = fdist[(size_t)pn * 16 + k];
    const float* cA = ctrA + (size_t)pn * 64;
    const float* nB = nbrB + ((size_t)b * NN + fnb) * 64;

    float fk[64];
#pragma unroll
    for (int o = 0; o < 64; ++o) {
        float y = cA[o] + nB[o] + w1d[o] * fd;
        float v = fmaf(g1[o] * BN_INV, y, b1[o]);
        fk[o] = v > 0.f ? v : 0.2f * v;
    }

    float cq[3], cn_[3];
#pragma unroll
    for (int j = 0; j < 3; ++j) cq[j] = coords[(size_t)pn * 3 + j];
    int cnb = knn_idx[(size_t)pn * 16 + k];
#pragma unroll
    for (int j = 0; j < 3; ++j) cn_[j] = coords[((size_t)b * NN + cnb) * 3 + j];
    float kd = knn_dist[(size_t)pn * 16 + k];

    float cp[13];
#pragma unroll
    for (int j = 0; j < 3; ++j) {
        float a = 0.f;
#pragma unroll
        for (int o = 0; o < 64; ++o) a = fmaf(W2[j * 64 + o], fk[o], a);
        float t = fmaf(g2[j] * BN_INV, a, b2[j]);
        t = t > 0.f ? t : __expf(t) - 1.f;  // elu
        cp[j] = cq[j];
        cp[3 + j] = cn_[j];
        cp[6 + j] = cq[j] - cn_[j];
        cp[10 + j] = t + cq[j];
    }
    cp[9] = kd;

    float fe[32];
#pragma unroll
    for (int c = 0; c < 32; ++c) {
        float a3 = 0.f, a4 = 0.f;
#pragma unroll
        for (int j = 0; j < 13; ++j) {
            a3 = fmaf(W3[c * 13 + j], cp[j], a3);
            a4 = fmaf(W4[c * 13 + j], cp[j], a4);
        }
        float po = fmaf(g3[c] * BN_INV, a3, b3[c]);
        po = po > 0.f ? po : __expf(po) - 1.f;
        fe[c] = po + feat[(b * 32 + c) * NN + n];
        float op = fmaf(g4[c] * BN_INV, a4, b4[c]);
        op = op > 0.f ? op : __expf(op) - 1.f;
        out[(((size_t)b * 64 + c) * NN + n) * 16 + k] = op;
    }

#pragma unroll
    for (int c = 0; c < 32; ++c) {
        float a5 = 0.f;
#pragma unroll
        for (int o = 0; o < 64; ++o) a5 = fmaf(W5[c * 96 + o], fk[o], a5);
#pragma unroll
        for (int j = 0; j < 32; ++j) a5 = fmaf(W5[c * 96 + 64 + j], fe[j], a5);
        float v = fmaf(g5[c] * BN_INV, a5, b5[c]);
        v = v > 0.f ? v : __expf(v) - 1.f;
        out[(((size_t)b * 64 + 32 + c) * NN + n) * 16 + k] = v;
    }
}

extern "C" void kernel_launch(void* const* d_in, const int* in_sizes, int n_in,
                              void* d_out, int out_size, void* d_ws, size_t ws_size,
                              hipStream_t stream) {
    const float* coords   = (const float*)d_in[0];
    const float* features = (const float*)d_in[1];
    const int*   knn_idx  = (const int*)d_in[2];
    const float* knn_dist = (const float*)d_in[3];
    const float* W1 = (const float*)d_in[4];
    const float* W2 = (const float*)d_in[5];
    const float* W3 = (const float*)d_in[6];
    const float* W4 = (const float*)d_in[7];
    const float* W5 = (const float*)d_in[8];
    const float* g1 = (const float*)d_in[9];
    const float* b1 = (const float*)d_in[10];
    const float* g2 = (const float*)d_in[11];
    const float* b2 = (const float*)d_in[12];
    const float* g3 = (const float*)d_in[13];
    const float* b3 = (const float*)d_in[14];
    const float* g4 = (const float*)d_in[15];
    const float* b4 = (const float*)d_in[16];
    const float* g5 = (const float*)d_in[17];
    const float* b5 = (const float*)d_in[18];
    float* out = (float*)d_out;

    // workspace layout (float slots)
    float*  pT    = (float*)d_ws;                  // 524288
    float*  sq32  = pT + BB * NN * 32;             // 16384
    double* sq64  = (double*)(sq32 + BB * NN);     // 16384 doubles (32768 slots)
    float*  fdist = (float*)(sq64 + BB * NN);      // 262144
    int*    fidx  = (int*)(fdist + BB * NN * 16);  // 262144
    float*  Aw    = (float*)(fidx + BB * NN * 16); // 2048
    float*  Bw    = Aw + 2048;                     // 2048
    float*  w1d   = Bw + 2048;                     // 64
    float*  ctrA  = w1d + 64;                      // B*N*64 = 1048576
    float*  nbrB  = ctrA + BB * NN * 64;           // B*N*64 = 1048576
    // pkey (RS*PK*B*N u32 = 33.5 MB) lives in d_out (67 MB): written by
    // knn_prefilter, read by knn_final, then fully overwritten by fuse_kernel.
    unsigned* pkey = (unsigned*)d_out;

    hipLaunchKernelGGL(p0_weights, dim3(1), dim3(256), 0, stream, W1, Aw, Bw, w1d);
    hipLaunchKernelGGL(p1_transpose, dim3(BB * NN / 256), dim3(256), 0, stream,
                       features, pT, sq32, sq64);
    hipLaunchKernelGGL(knn_prefilter, dim3(BB * NN / 256, RS), dim3(256), 0, stream,
                       pT, sq32, pkey);
    hipLaunchKernelGGL(knn_final, dim3(BB * NN / 64), dim3(64), 0, stream,
                       pT, sq64, pkey, fidx, fdist);
    hipLaunchKernelGGL(p2_proj, dim3(BB * NN * 64 / 256), dim3(256), 0, stream,
                       pT, Aw, Bw, ctrA, nbrB);
    hipLaunchKernelGGL(fuse_kernel, dim3(BB * NN * KK / 256), dim3(256), 0, stream,
                       coords, features, knn_idx, knn_dist, W2, W3, W4, W5,
                       g1, b1, g2, b2, g3, b3, g4, b4, g5, b5,
                       ctrA, nbrB, w1d, fidx, fdist, out);
}

// Round 6
// 390.394 us; speedup vs baseline: 2.7468x; 1.3836x over previous
//
#include <hip/hip_runtime.h>
#include <math.h>

#define BB 4
#define NN 4096
#define KK 16
#define CIN 32
#define COUT 64
#define BN_INV 0.9999950000375f

#define RS 32    // candidate ranges per query
#define PCH 128  // candidates per range (NN/RS)
#define PK 16    // prefilter top-K per range
#define NK2 24   // candidates sent to fp64 rerank

typedef float f32x2 __attribute__((ext_vector_type(2)));

// ---------------- P0: derived W1 weights ----------------
__global__ void p0_weights(const float* __restrict__ W1,
                           float* __restrict__ Aw, float* __restrict__ Bw,
                           float* __restrict__ w1d) {
    int t = threadIdx.x;
    for (int i = t; i < 64 * 32; i += 256) {
        int o = i >> 5, c = i & 31;
        Aw[i] = W1[o * 128 + c] - W1[o * 128 + 64 + c];
        Bw[i] = W1[o * 128 + 32 + c] + W1[o * 128 + 64 + c];
    }
    if (t < 64) {
        float s = 0.f;
        for (int c = 96; c < 128; ++c) s += W1[t * 128 + c];
        w1d[t] = s;
    }
}

// ---------------- P1: transpose features to [B,N,32] + fp32/fp64 norms ----------------
__global__ void p1_transpose(const float* __restrict__ f, float* __restrict__ pT,
                             float* __restrict__ sq32, double* __restrict__ sq64) {
    int g = blockIdx.x * 256 + threadIdx.x;  // b*N + n
    int b = g >> 12, n = g & (NN - 1);
    float v[CIN];
#pragma unroll
    for (int c = 0; c < CIN; ++c) v[c] = f[(b * CIN + c) * NN + n];
#pragma unroll
    for (int c = 0; c < CIN; ++c) pT[(size_t)g * CIN + c] = v[c];
    // 4-accumulator chain — BITWISE identical to knn_prefilter's pk_fma dot chain
    // (pk_fma lane = scalar fma; pairing (a0+a1)+(a2+a3) preserved)
    float a0 = 0.f, a1 = 0.f, a2 = 0.f, a3 = 0.f;
#pragma unroll
    for (int c4 = 0; c4 < 8; ++c4) {
        a0 = fmaf(v[4 * c4 + 0], v[4 * c4 + 0], a0);
        a1 = fmaf(v[4 * c4 + 1], v[4 * c4 + 1], a1);
        a2 = fmaf(v[4 * c4 + 2], v[4 * c4 + 2], a2);
        a3 = fmaf(v[4 * c4 + 3], v[4 * c4 + 3], a3);
    }
    sq32[g] = (a0 + a1) + (a2 + a3);
    // sequential fp64 chain — must match knn_final's rerank chains
    double s64 = 0.0;
#pragma unroll
    for (int c = 0; c < CIN; ++c) s64 = fma((double)v[c], (double)v[c], s64);
    sq64[g] = s64;
}

// ---------------- P2: per-point projections ctrA = A*p, nbrB = B*p ----------------
__global__ __launch_bounds__(256) void p2_proj(const float* __restrict__ pT,
                                               const float* __restrict__ Aw,
                                               const float* __restrict__ Bw,
                                               float* __restrict__ ctrA,
                                               float* __restrict__ nbrB) {
    __shared__ float sA[32 * 64], sB[32 * 64];
    for (int i = threadIdx.x; i < 2048; i += 256) {
        int o = i >> 5, c = i & 31;
        sA[c * 64 + o] = Aw[i];
        sB[c * 64 + o] = Bw[i];
    }
    __syncthreads();
    int g = blockIdx.x * 256 + threadIdx.x;  // (b*N+n)*64 + o
    int o = g & 63;
    int pn = g >> 6;
    const float* p = pT + (size_t)pn * 32;
    float a = 0.f, bb = 0.f;
#pragma unroll
    for (int c = 0; c < 32; ++c) {
        float pv = p[c];
        a = fmaf(sA[c * 64 + o], pv, a);
        bb = fmaf(sB[c * 64 + o], pv, bb);
    }
    ctrA[g] = a;
    nbrB[g] = bb;
}

// ---------------- KNN prefilter: LDS-staged tile + pk_fma dot + packed-key top-16 ----
__global__ __launch_bounds__(256) void knn_prefilter(const float* __restrict__ pT,
                                                     const float* __restrict__ sq32,
                                                     unsigned* __restrict__ pkey) {
    __shared__ float tile[PCH * 32];   // 16 KB candidate tile
    __shared__ float tsq[PCH];         // 512 B norms
    int tid = threadIdx.x;
    int n = blockIdx.x * 256 + tid;    // global point id (b*N+nb)
    int b = n >> 12;
    const float* pb = pT + ((size_t)(b << 12)) * 32;
    int m0 = blockIdx.y * PCH;

    // stage this block's candidate range into LDS (coalesced)
    {
        const float4* src = (const float4*)(pb + (size_t)m0 * 32);
        float4* dst = (float4*)tile;
#pragma unroll
        for (int i = 0; i < (PCH * 8) / 256; ++i) dst[tid + 256 * i] = src[tid + 256 * i];
        if (tid < PCH) tsq[tid] = sq32[(b << 12) + m0 + tid];
    }

    // query vector as f32x2 pairs
    f32x2 qv[16];
    {
        const float4* q4 = (const float4*)(pT + (size_t)n * 32);
#pragma unroll
        for (int c4 = 0; c4 < 8; ++c4) {
            float4 t = q4[c4];
            qv[2 * c4 + 0] = (f32x2){t.x, t.y};
            qv[2 * c4 + 1] = (f32x2){t.z, t.w};
        }
    }
    float negsqn = -sq32[n];
    unsigned key[PK];
#pragma unroll
    for (int i = 0; i < PK; ++i) key[i] = 0u;

    __syncthreads();

#pragma unroll 2
    for (int mm = 0; mm < PCH; ++mm) {
        const float4* row = (const float4*)(tile + mm * 32);  // wave-uniform -> broadcast
        f32x2 a01 = {0.f, 0.f}, a23 = {0.f, 0.f};
#pragma unroll
        for (int c4 = 0; c4 < 8; ++c4) {
            float4 t = row[c4];
            a01 = __builtin_elementwise_fma((f32x2){t.x, t.y}, qv[2 * c4 + 0], a01);
            a23 = __builtin_elementwise_fma((f32x2){t.z, t.w}, qv[2 * c4 + 1], a23);
        }
        float dot = (a01.x + a01.y) + (a23.x + a23.y);
        // self: dot == sq32[n] bitwise (identical chain); fmaf(2,dot,-2*sq) == 0 exactly
        float d = fmaf(2.f, dot, negsqn - tsq[mm]);
        unsigned u = __float_as_uint(d);
        unsigned k32 = u ^ (unsigned)(((int)u >> 31) | 0x80000000);
        unsigned cv = (k32 & 0xFFFFF000u) | (unsigned)(4095 - (m0 + mm));
        // branchless 16-deep sorted insert
#pragma unroll
        for (int j = 0; j < PK; ++j) {
            unsigned vj = key[j];
            unsigned hi = cv > vj ? cv : vj;
            unsigned lo = cv > vj ? vj : cv;
            key[j] = hi; cv = lo;
        }
    }
    // layout [r][k][B*N] for coalesced read in knn_final
    size_t base = (size_t)blockIdx.y * PK * (BB * NN) + n;
#pragma unroll
    for (int i = 0; i < PK; ++i) pkey[base + (size_t)i * (BB * NN)] = key[i];
}

// ---------------- KNN final: key-select top-24, fp64 exact rerank -> top-16 ----------------
__global__ __launch_bounds__(64) void knn_final(const float* __restrict__ pT,
                                                const double* __restrict__ sq64,
                                                const unsigned* __restrict__ pkey,
                                                int* __restrict__ fidx,
                                                float* __restrict__ fdist) {
    int n = blockIdx.x * 64 + threadIdx.x;
    int b = n >> 12;
    const float* pb = pT + ((size_t)(b << 12)) * 32;
    const double* sqb = sq64 + (b << 12);

    // select top-NK2 keys of RS*PK candidates; per-range keys arrive sorted desc,
    // so once no lane in the wave can insert, the rest of the range is skippable.
    unsigned sk[NK2];
#pragma unroll
    for (int i = 0; i < NK2; ++i) sk[i] = 0u;
    for (int r = 0; r < RS; ++r) {
        unsigned kv[PK];
#pragma unroll
        for (int k = 0; k < PK; ++k)
            kv[k] = pkey[(size_t)(r * PK + k) * (BB * NN) + n];  // coalesced batch
        for (int k = 0; k < PK; ++k) {
            unsigned cv = kv[k];
            if (__all(cv <= sk[NK2 - 1])) break;  // lane-keys descend within range
#pragma unroll
            for (int j = 0; j < NK2; ++j) {
                unsigned vj = sk[j];
                unsigned hi = cv > vj ? cv : vj;
                unsigned lo = cv > vj ? vj : cv;
                sk[j] = hi; cv = lo;
            }
        }
    }

    // fp64 exact rerank of the NK2 survivors (chains identical to R2's passing kernel)
    double qv[32];
    const float4* q4 = (const float4*)(pT + (size_t)n * 32);
#pragma unroll
    for (int c4 = 0; c4 < 8; ++c4) {
        float4 t = q4[c4];
        qv[4 * c4] = (double)t.x; qv[4 * c4 + 1] = (double)t.y;
        qv[4 * c4 + 2] = (double)t.z; qv[4 * c4 + 3] = (double)t.w;
    }
    double sqn = 0.0;
#pragma unroll
    for (int c = 0; c < 32; ++c) sqn = fma(qv[c], qv[c], sqn);

    double dv[16];
    int di[16];
#pragma unroll
    for (int i = 0; i < 16; ++i) { dv[i] = -1e300; di[i] = 0x7fffffff; }
#pragma unroll
    for (int u = 0; u < NK2; ++u) {
        int m = 4095 - (int)(sk[u] & 0xFFFu);
        const float4* row = (const float4*)(pb + (size_t)m * 32);
        double dot = 0.0;
#pragma unroll
        for (int c4 = 0; c4 < 8; ++c4) {
            float4 t = row[c4];
            dot = fma((double)t.x, qv[4 * c4], dot);
            dot = fma((double)t.y, qv[4 * c4 + 1], dot);
            dot = fma((double)t.z, qv[4 * c4 + 2], dot);
            dot = fma((double)t.w, qv[4 * c4 + 3], dot);
        }
        double d = 2.0 * dot - sqn - sqb[m];  // self -> exactly 0
        if (d > dv[15] || (d == dv[15] && m < di[15])) {
            double cv = d; int ci = m;
#pragma unroll
            for (int j = 0; j < 16; ++j) {
                bool c = (cv > dv[j]) || (cv == dv[j] && ci < di[j]);
                double nv = c ? cv : dv[j]; double nc = c ? dv[j] : cv;
                int ni = c ? ci : di[j];    int nj = c ? di[j] : ci;
                dv[j] = nv; cv = nc; di[j] = ni; ci = nj;
            }
        }
    }
#pragma unroll
    for (int i = 0; i < 16; ++i) {
        fdist[(size_t)n * 16 + i] = (float)dv[i];
        fidx[(size_t)n * 16 + i] = di[i];
    }
}

// ---------------- Fused main pipeline: one thread per (b,n,k) ----------------
__global__ __launch_bounds__(256) void fuse_kernel(
    const float* __restrict__ coords, const float* __restrict__ feat,
    const int* __restrict__ knn_idx, const float* __restrict__ knn_dist,
    const float* __restrict__ W2, const float* __restrict__ W3,
    const float* __restrict__ W4, const float* __restrict__ W5,
    const float* __restrict__ g1, const float* __restrict__ b1,
    const float* __restrict__ g2, const float* __restrict__ b2,
    const float* __restrict__ g3, const float* __restrict__ b3,
    const float* __restrict__ g4, const float* __restrict__ b4,
    const float* __restrict__ g5, const float* __restrict__ b5,
    const float* __restrict__ ctrA, const float* __restrict__ nbrB,
    const float* __restrict__ w1d, const int* __restrict__ fidx,
    const float* __restrict__ fdist, float* __restrict__ out) {
    int g = blockIdx.x * 256 + threadIdx.x;
    int k = g & 15;
    int n = (g >> 4) & (NN - 1);
    int b = g >> 16;
    int pn = b * NN + n;

    int fnb = fidx[(size_t)pn * 16 + k];
    float fd = fdist[(size_t)pn * 16 + k];
    const float* cA = ctrA + (size_t)pn * 64;
    const float* nB = nbrB + ((size_t)b * NN + fnb) * 64;

    float fk[64];
#pragma unroll
    for (int o = 0; o < 64; ++o) {
        float y = cA[o] + nB[o] + w1d[o] * fd;
        float v = fmaf(g1[o] * BN_INV, y, b1[o]);
        fk[o] = v > 0.f ? v : 0.2f * v;
    }

    float cq[3], cn_[3];
#pragma unroll
    for (int j = 0; j < 3; ++j) cq[j] = coords[(size_t)pn * 3 + j];
    int cnb = knn_idx[(size_t)pn * 16 + k];
#pragma unroll
    for (int j = 0; j < 3; ++j) cn_[j] = coords[((size_t)b * NN + cnb) * 3 + j];
    float kd = knn_dist[(size_t)pn * 16 + k];

    float cp[13];
#pragma unroll
    for (int j = 0; j < 3; ++j) {
        float a = 0.f;
#pragma unroll
        for (int o = 0; o < 64; ++o) a = fmaf(W2[j * 64 + o], fk[o], a);
        float t = fmaf(g2[j] * BN_INV, a, b2[j]);
        t = t > 0.f ? t : __expf(t) - 1.f;  // elu
        cp[j] = cq[j];
        cp[3 + j] = cn_[j];
        cp[6 + j] = cq[j] - cn_[j];
        cp[10 + j] = t + cq[j];
    }
    cp[9] = kd;

    float fe[32];
#pragma unroll
    for (int c = 0; c < 32; ++c) {
        float a3 = 0.f, a4 = 0.f;
#pragma unroll
        for (int j = 0; j < 13; ++j) {
            a3 = fmaf(W3[c * 13 + j], cp[j], a3);
            a4 = fmaf(W4[c * 13 + j], cp[j], a4);
        }
        float po = fmaf(g3[c] * BN_INV, a3, b3[c]);
        po = po > 0.f ? po : __expf(po) - 1.f;
        fe[c] = po + feat[(b * 32 + c) * NN + n];
        float op = fmaf(g4[c] * BN_INV, a4, b4[c]);
        op = op > 0.f ? op : __expf(op) - 1.f;
        out[(((size_t)b * 64 + c) * NN + n) * 16 + k] = op;
    }

#pragma unroll
    for (int c = 0; c < 32; ++c) {
        float a5 = 0.f;
#pragma unroll
        for (int o = 0; o < 64; ++o) a5 = fmaf(W5[c * 96 + o], fk[o], a5);
#pragma unroll
        for (int j = 0; j < 32; ++j) a5 = fmaf(W5[c * 96 + 64 + j], fe[j], a5);
        float v = fmaf(g5[c] * BN_INV, a5, b5[c]);
        v = v > 0.f ? v : __expf(v) - 1.f;
        out[(((size_t)b * 64 + 32 + c) * NN + n) * 16 + k] = v;
    }
}

extern "C" void kernel_launch(void* const* d_in, const int* in_sizes, int n_in,
                              void* d_out, int out_size, void* d_ws, size_t ws_size,
                              hipStream_t stream) {
    const float* coords   = (const float*)d_in[0];
    const float* features = (const float*)d_in[1];
    const int*   knn_idx  = (const int*)d_in[2];
    const float* knn_dist = (const float*)d_in[3];
    const float* W1 = (const float*)d_in[4];
    const float* W2 = (const float*)d_in[5];
    const float* W3 = (const float*)d_in[6];
    const float* W4 = (const float*)d_in[7];
    const float* W5 = (const float*)d_in[8];
    const float* g1 = (const float*)d_in[9];
    const float* b1 = (const float*)d_in[10];
    const float* g2 = (const float*)d_in[11];
    const float* b2 = (const float*)d_in[12];
    const float* g3 = (const float*)d_in[13];
    const float* b3 = (const float*)d_in[14];
    const float* g4 = (const float*)d_in[15];
    const float* b4 = (const float*)d_in[16];
    const float* g5 = (const float*)d_in[17];
    const float* b5 = (const float*)d_in[18];
    float* out = (float*)d_out;

    // workspace layout (float slots)
    float*  pT    = (float*)d_ws;                  // 524288
    float*  sq32  = pT + BB * NN * 32;             // 16384
    double* sq64  = (double*)(sq32 + BB * NN);     // 16384 doubles (32768 slots)
    float*  fdist = (float*)(sq64 + BB * NN);      // 262144
    int*    fidx  = (int*)(fdist + BB * NN * 16);  // 262144
    float*  Aw    = (float*)(fidx + BB * NN * 16); // 2048
    float*  Bw    = Aw + 2048;                     // 2048
    float*  w1d   = Bw + 2048;                     // 64
    float*  ctrA  = w1d + 64;                      // B*N*64 = 1048576
    float*  nbrB  = ctrA + BB * NN * 64;           // B*N*64 = 1048576
    // pkey (RS*PK*B*N u32 = 33.5 MB) lives in d_out (67 MB): written by
    // knn_prefilter, read by knn_final, then fully overwritten by fuse_kernel.
    unsigned* pkey = (unsigned*)d_out;

    hipLaunchKernelGGL(p0_weights, dim3(1), dim3(256), 0, stream, W1, Aw, Bw, w1d);
    hipLaunchKernelGGL(p1_transpose, dim3(BB * NN / 256), dim3(256), 0, stream,
                       features, pT, sq32, sq64);
    hipLaunchKernelGGL(knn_prefilter, dim3(BB * NN / 256, RS), dim3(256), 0, stream,
                       pT, sq32, pkey);
    hipLaunchKernelGGL(knn_final, dim3(BB * NN / 64), dim3(64), 0, stream,
                       pT, sq64, pkey, fidx, fdist);
    hipLaunchKernelGGL(p2_proj, dim3(BB * NN * 64 / 256), dim3(256), 0, stream,
                       pT, Aw, Bw, ctrA, nbrB);
    hipLaunchKernelGGL(fuse_kernel, dim3(BB * NN * KK / 256), dim3(256), 0, stream,
                       coords, features, knn_idx, knn_dist, W2, W3, W4, W5,
                       g1, b1, g2, b2, g3, b3, g4, b4, g5, b5,
                       ctrA, nbrB, w1d, fidx, fdist, out);
}